// Round 5
// baseline (228.857 us; speedup 1.0000x reference)
//
#include <hip/hip_runtime.h>
#include <hip/hip_bf16.h>
#include <math.h>

// Shapes: x(8,64,128,128) f32; wt(4,4,64,64,3,3) f32; attn_w(4,64); attn_b(4)
// Subband space: 64x64, 4 subbands, 64 cin, 64 cout.
// feats layout: [b][sub][66][66][64c] bf16, zero border ring (pad=1).
// Single fused kernel: DWT -> swbarrier -> mix -> swbarrier -> conv+IDWT.
// Software grid barrier: 512 blocks x 2/CU co-resident by LDS capacity
// (61.4 KB/block, 160 KB/CU). Barrier state lives in the WORKSPACE (never in
// `out` -- timed replays do not re-zero out, and barrier atomics racing the
// owner's epilogue corrupted the readback in round 4). A tiny init kernel
// zeroes the 2 barrier words before every fused launch.

typedef __bf16 bf16x8 __attribute__((ext_vector_type(8)));
typedef float f32x4 __attribute__((ext_vector_type(4)));

__device__ __forceinline__ bf16x8 as_bf16x8(uint4 u) {
    union { uint4 a; bf16x8 b; } c; c.a = u; return c.b;
}
__device__ __forceinline__ unsigned short bf16bits(float f) {
    __hip_bfloat16 h = __float2bfloat16(f);
    union { __hip_bfloat16 h; unsigned short u; } c; c.h = h; return c.u;
}
// async 16B global -> LDS (DMA; LDS dest = wave-uniform base + lane*16)
__device__ __forceinline__ void gload_lds16(const uint4* g, uint4* l) {
    __builtin_amdgcn_global_load_lds(
        (const __attribute__((address_space(1))) unsigned int*)g,
        (__attribute__((address_space(3))) unsigned int*)l, 16, 0, 0);
}

#define FPLANE 34848   // 66*66*8 uint4 per (b,sub) plane
#define FROW   528     // 66*8

// -------- software grid barrier (all blocks co-resident by capacity) -------
__device__ __forceinline__ void gbar(unsigned* ctr, unsigned* rel,
                                     unsigned target, unsigned gen) {
    __syncthreads();
    if (threadIdx.x == 0) {
        __threadfence();                       // release: publish this block's writes
        unsigned old = atomicAdd(ctr, 1u);     // device-scope RMW (coherent)
        if (old == target - 1u) {
            __hip_atomic_store(rel, gen, __ATOMIC_RELEASE,
                               __HIP_MEMORY_SCOPE_AGENT);
        } else {
            while (__hip_atomic_load(rel, __ATOMIC_ACQUIRE,
                                     __HIP_MEMORY_SCOPE_AGENT) < gen)
                __builtin_amdgcn_s_sleep(4);
        }
        __threadfence();                       // acquire: invalidate stale lines
    }
    __syncthreads();
}

__global__ void binit_kernel(unsigned* p) {
    __hip_atomic_store(&p[0], 0u, __ATOMIC_RELAXED, __HIP_MEMORY_SCOPE_AGENT);
    __hip_atomic_store(&p[1], 0u, __ATOMIC_RELAXED, __HIP_MEMORY_SCOPE_AGENT);
}

// A halo: 10x18 px * 4 g-chunks (32 ci) = 720 uint4; padded to 768
// (e 720..767 read row y0+10 -- garbage within allocated ws, never consumed)
__device__ __forceinline__ void stage_A(const uint4* __restrict__ fp, uint4* sAb,
                                        int y0, int x0, int ck8, int t) {
    #pragma unroll
    for (int i = 0; i < 3; ++i) {
        int e = t + i * 256;
        int py = e / 72, rr = e - py * 72, px = rr >> 2, g = rr & 3;
        gload_lds16(fp + (size_t)((y0 + py) * 66 + x0 + px) * 8 + ck8 + g, &sAb[e]);
    }
}
// W: 9 taps x 32 co (this cg half) x 32 ci = 1152 uint4
__device__ __forceinline__ void stage_W(const uint4* __restrict__ wch, uint4* sWb,
                                        int cgv, int ck8, int t) {
    #pragma unroll
    for (int i = 0; i < 4; ++i) {
        int e = t + i * 256;
        int tap = e >> 7, rr = e & 127, co = rr >> 2, g = rr & 3;
        gload_lds16(wch + tap * 512 + (cgv * 32 + co) * 8 + ck8 + g, &sWb[e]);
    }
    if (t < 128) {                                  // tail: waves 0,1 (wave-uniform)
        int e = 1024 + t;
        int tap = e >> 7, rr = e & 127, co = rr >> 2, g = rr & 3;
        gload_lds16(wch + tap * 512 + (cgv * 32 + co) * 8 + ck8 + g, &sWb[e]);
    }
}

// LDS union (61440 B total, 2 blocks/CU):
//   DWT : sT uint4[2304] @0 (36864B), sred float[64][4] @36864 (1024B)
//   mix : sLw float[4][576] @24576 (9216B), satt float[4][4] @33792
//   conv: sA uint4[2][768] @0 (24576B), sW uint4[2][1152] @24576 (36864B)
// (mix lives in the sW region so the conv A-halo prefetch can run during mix)
__global__ __launch_bounds__(256, 2)
void fused_kernel(const float* __restrict__ x, const float* __restrict__ wt,
                  const float* __restrict__ attn_w, const float* __restrict__ attn_b,
                  float* __restrict__ plog, unsigned short* __restrict__ feats,
                  unsigned short* __restrict__ wmix, unsigned* __restrict__ bstate,
                  float* __restrict__ out) {
    __shared__ uint4 smem[3840];
    int lin = blockIdx.x, t = threadIdx.x;
    unsigned* bctr = bstate;
    unsigned* brel = bstate + 1;

    // ------------------------- Phase A: Haar DWT --------------------------
    {
        uint4* sT = smem;
        unsigned short* sTu = (unsigned short*)smem;
        float (*sred)[4] = (float(*)[4])((char*)smem + 36864);
        int y = lin >> 3, b = lin & 7;
        int c = t >> 2, q = t & 3;

        const float4* r0 = (const float4*)x + ((size_t)(b * 64 + c) * 128 + 2 * y) * 32;
        const float4* r1 = r0 + 32;

        float s0 = 0.f, s1 = 0.f, s2 = 0.f, s3 = 0.f;
        #pragma unroll
        for (int i = 0; i < 8; ++i) {
            int f = i * 4 + q;                     // quad covers 64B contiguous
            float4 p = r0[f], qq = r1[f];
            int xo = 2 * f;
            {
                float a = p.x, bb = p.y, cc = qq.x, dd = qq.y;
                float ll = (a + bb + cc + dd) * 0.5f, h0 = (a + bb - cc - dd) * 0.5f;
                float h1 = (a - bb + cc - dd) * 0.5f, hh = (a - bb - cc + dd) * 0.5f;
                s0 += ll; s1 += h0; s2 += h1; s3 += hh;
                sTu[0 * 4608 + xo * 72 + c] = bf16bits(ll);
                sTu[1 * 4608 + xo * 72 + c] = bf16bits(h0);
                sTu[2 * 4608 + xo * 72 + c] = bf16bits(h1);
                sTu[3 * 4608 + xo * 72 + c] = bf16bits(hh);
            }
            {
                float a = p.z, bb = p.w, cc = qq.z, dd = qq.w;
                float ll = (a + bb + cc + dd) * 0.5f, h0 = (a + bb - cc - dd) * 0.5f;
                float h1 = (a - bb + cc - dd) * 0.5f, hh = (a - bb - cc + dd) * 0.5f;
                s0 += ll; s1 += h0; s2 += h1; s3 += hh;
                sTu[0 * 4608 + (xo + 1) * 72 + c] = bf16bits(ll);
                sTu[1 * 4608 + (xo + 1) * 72 + c] = bf16bits(h0);
                sTu[2 * 4608 + (xo + 1) * 72 + c] = bf16bits(h1);
                sTu[3 * 4608 + (xo + 1) * 72 + c] = bf16bits(hh);
            }
        }
        s0 += __shfl_xor(s0, 1); s0 += __shfl_xor(s0, 2);
        s1 += __shfl_xor(s1, 1); s1 += __shfl_xor(s1, 2);
        s2 += __shfl_xor(s2, 1); s2 += __shfl_xor(s2, 2);
        s3 += __shfl_xor(s3, 1); s3 += __shfl_xor(s3, 2);
        if (q == 0) { sred[c][0] = s0; sred[c][1] = s1; sred[c][2] = s2; sred[c][3] = s3; }
        __syncthreads();
        if (t < 16) {
            int sub = t >> 2, k = t & 3;
            float acc = 0.f;
            #pragma unroll 8
            for (int cc = 0; cc < 64; ++cc)
                acc += attn_w[k * 64 + cc] * sred[cc][sub];
            plog[((size_t)(b * 4 + sub) * 4 + k) * 64 + y] = acc;
        }
        // padded channel-last writes: row y+1 of each plane, zero side borders
        uint4* fpad = (uint4*)feats;
        const uint4 zz = make_uint4(0u, 0u, 0u, 0u);
        for (int e = t; e < 2112; e += 256) {
            int s = e / 528, r = e - s * 528;
            int px = r >> 3, ck = r & 7;
            uint4 v = zz;
            if (px >= 1 && px <= 64) v = sT[s * 576 + (px - 1) * 9 + ck];
            fpad[((size_t)(b * 4 + s) * 66 + (y + 1)) * FROW + r] = v;
        }
        if (y == 0) {
            for (int e = t; e < 2112; e += 256) {
                int s = e / 528, r = e - s * 528;
                fpad[(size_t)(b * 4 + s) * 66 * FROW + r] = zz;
            }
        } else if (y == 63) {
            for (int e = t; e < 2112; e += 256) {
                int s = e / 528, r = e - s * 528;
                fpad[((size_t)(b * 4 + s) * 66 + 65) * FROW + r] = zz;
            }
        }
    }
    gbar(bctr, brel, 512u, 1u);

    // conv-phase indices (needed for the early A prefetch)
    int b2 = lin & 7;                  // XCD-chunked: XCD k -> batch k
    int rest = lin >> 3;               // [0,64)
    int cgv = rest >> 5, tile = rest & 31;
    int y0 = (tile >> 2) * 8, x0 = (tile & 3) * 16;
    uint4* sA = smem;                  // 2 x 768 uint4
    uint4* sW = smem + 1536;           // 2 x 1152 uint4
    const uint4* fpb = (const uint4*)feats + (size_t)b2 * 4 * FPLANE;
    const uint4* wcb = (const uint4*)wmix + (size_t)b2 * 4 * 4608;

    // prefetch conv phase-0 A halo NOW (feats ready; mix uses the sW region)
    stage_A(fpb, sA, y0, x0, 0, t);

    // ------------------- Phase B: attention + kernel mix ------------------
    {
        float* sLw = (float*)(smem + 1536);                  // [4][576]
        float* satt = (float*)((char*)(smem + 1536) + 9216); // [4 b-local][4 k]
        int unit = lin & 255, bb0 = (lin >> 8) * 4;          // b half per block
        int co = unit & 63, sub = unit >> 6;
        if (t < 16) {
            int bl = t >> 2, k = t & 3, b = bb0 + bl;
            const float* pp = plog + ((size_t)(b * 4 + sub) * 4 + k) * 64;
            float acc = 0.f;
            #pragma unroll 8
            for (int yy = 0; yy < 64; ++yy) acc += pp[yy];
            float logit = acc * (1.0f / 4096.0f) + attn_b[k];
            float m = fmaxf(logit, __shfl_xor(logit, 1));
            m = fmaxf(m, __shfl_xor(m, 2));
            float e = expf(logit - m);
            float s = e + __shfl_xor(e, 1);
            s += __shfl_xor(s, 2);
            satt[bl * 4 + k] = e / s;
        }
        for (int e = t; e < 2304; e += 256) {
            int k = e / 576, r = e - k * 576;
            sLw[k * 576 + r] = wt[((size_t)(k * 4 + sub) * 64 + co) * 576 + r];
        }
        __syncthreads();
        #pragma unroll
        for (int j = 0; j < 9; ++j) {
            int idx = j * 256 + t;                 // [0,2304) = 4 b-local * 576
            int bl = idx / 576;
            int r = idx - bl * 576;
            int tap = r >> 6, ci = r & 63;
            int wi = ci * 9 + tap;
            float v = satt[bl * 4 + 0] * sLw[0 * 576 + wi]
                    + satt[bl * 4 + 1] * sLw[1 * 576 + wi]
                    + satt[bl * 4 + 2] * sLw[2 * 576 + wi]
                    + satt[bl * 4 + 3] * sLw[3 * 576 + wi];
            wmix[((size_t)((bb0 + bl) * 4 + sub) * 9 + tap) * 4096 + co * 64 + ci] =
                bf16bits(v);
        }
    }
    gbar(bctr, brel, 1024u, 2u);

    // --------------------- Phase C: conv + Haar IDWT ----------------------
    int w = t >> 6, l = t & 63;
    int l16 = l & 15, kg = l >> 4;
    int wy4 = (w >> 1) * 4, wn = w & 1;

    f32x4 accQ[4][4];                  // [quad a,b,c,d][r]
    f32x4 accS[4];                     // current-subband conv accumulator
    #pragma unroll
    for (int qd = 0; qd < 4; ++qd)
        #pragma unroll
        for (int r = 0; r < 4; ++r)
            accQ[qd][r] = (f32x4){0.f, 0.f, 0.f, 0.f};
    #pragma unroll
    for (int r = 0; r < 4; ++r) accS[r] = (f32x4){0.f, 0.f, 0.f, 0.f};

    stage_W(wcb, sW, cgv, 0, t);       // W phase 0 (A phase 0 already in flight)
    __syncthreads();

    #pragma unroll
    for (int p = 0; p < 8; ++p) {
        const int sub = p >> 1;
        // issue next phase's loads first -- they land during the MFMA stretch
        if (p < 7) {
            const int ns = (p + 1) >> 1, nc = ((p + 1) & 1) * 4;
            stage_A(fpb + (size_t)ns * FPLANE, sA + ((p + 1) & 1) * 768, y0, x0, nc, t);
            stage_W(wcb + (size_t)ns * 4608, sW + ((p + 1) & 1) * 1152, cgv, nc, t);
        }
        // compute current phase from buffer p&1
        {
            const uint4* A = sA + (p & 1) * 768;
            const uint4* W = sW + (p & 1) * 1152;
            uint4 af[4][3];
            #pragma unroll
            for (int i = 0; i < 4; ++i)
                #pragma unroll
                for (int dx = 0; dx < 3; ++dx)
                    af[i][dx] = A[((wy4 + i) * 18 + l16 + dx) * 4 + kg];
            __builtin_amdgcn_s_setprio(1);
            #pragma unroll
            for (int dy = 0; dy < 3; ++dy) {
                if (dy > 0) {
                    #pragma unroll
                    for (int i = 0; i < 3; ++i)
                        #pragma unroll
                        for (int dx = 0; dx < 3; ++dx)
                            af[i][dx] = af[i + 1][dx];
                    #pragma unroll
                    for (int dx = 0; dx < 3; ++dx)
                        af[3][dx] = A[((wy4 + dy + 3) * 18 + l16 + dx) * 4 + kg];
                }
                #pragma unroll
                for (int dx = 0; dx < 3; ++dx) {
                    int tap = dy * 3 + dx;
                    bf16x8 bw = as_bf16x8(W[tap * 128 + (wn * 16 + l16) * 4 + kg]);
                    #pragma unroll
                    for (int r = 0; r < 4; ++r)
                        accS[r] = __builtin_amdgcn_mfma_f32_16x16x32_bf16(
                            as_bf16x8(af[r][dx]), bw, accS[r], 0, 0, 0);
                }
            }
            __builtin_amdgcn_s_setprio(0);
        }
        // end of subband: fold into quad accumulators with IDWT signs
        // a: + + + +   b: + + - -   c: + - + -   d: + - - +   (over ll,h0,h1,hh)
        if (p & 1) {
            const float g1 = (sub <= 1) ? 1.f : -1.f;
            const float g2 = (sub == 0 || sub == 2) ? 1.f : -1.f;
            const float g3 = (sub == 0 || sub == 3) ? 1.f : -1.f;
            #pragma unroll
            for (int r = 0; r < 4; ++r) {
                #pragma unroll
                for (int j = 0; j < 4; ++j) {
                    float v = accS[r][j];
                    accQ[0][r][j] += v;
                    accQ[1][r][j] += g1 * v;
                    accQ[2][r][j] += g2 * v;
                    accQ[3][r][j] += g3 * v;
                    accS[r][j] = 0.f;
                }
            }
        }
        __syncthreads();
    }

    // epilogue: D row=(lane>>4)*4+reg = x offset, col=lane&15 = co (within 16)
    // subband pixel (y,x) -> out rows 2y (a,b interleaved), 2y+1 (c,d)
    #pragma unroll
    for (int r = 0; r < 4; ++r) {
        int y = y0 + wy4 + r;
        int co = cgv * 32 + wn * 16 + l16;
        float* otop = out + ((size_t)(b2 * 64 + co) * 128 + 2 * y) * 128
                          + 2 * (x0 + kg * 4);
        float* obot = otop + 128;
        #pragma unroll
        for (int jp = 0; jp < 2; ++jp) {
            float4 vt, vb;
            vt.x = 0.5f * accQ[0][r][2 * jp];
            vt.y = 0.5f * accQ[1][r][2 * jp];
            vt.z = 0.5f * accQ[0][r][2 * jp + 1];
            vt.w = 0.5f * accQ[1][r][2 * jp + 1];
            vb.x = 0.5f * accQ[2][r][2 * jp];
            vb.y = 0.5f * accQ[3][r][2 * jp];
            vb.z = 0.5f * accQ[2][r][2 * jp + 1];
            vb.w = 0.5f * accQ[3][r][2 * jp + 1];
            *(float4*)(otop + 4 * jp) = vt;
            *(float4*)(obot + 4 * jp) = vb;
        }
    }
}

// ---------------------------------------------------------------------------
extern "C" void kernel_launch(void* const* d_in, const int* in_sizes, int n_in,
                              void* d_out, int out_size, void* d_ws, size_t ws_size,
                              hipStream_t stream) {
    const float* x  = (const float*)d_in[0];
    const float* wt = (const float*)d_in[1];
    const float* aw = (const float*)d_in[2];
    const float* ab = (const float*)d_in[3];
    float* out = (float*)d_out;
    char* ws = (char*)d_ws;

    float* plog           = (float*)ws;                              // 32,768 B
    unsigned short* feats = (unsigned short*)(ws + 32768);           // 17,842,176 B (padded)
    unsigned short* wmix  = (unsigned short*)(ws + 32768 + 17842176);// 2,359,296 B
    unsigned* bstate      = (unsigned*)(ws + 32768 + 17842176 + 2359296); // 16 B

    hipLaunchKernelGGL(binit_kernel, dim3(1), dim3(1), 0, stream, bstate);
    hipLaunchKernelGGL(fused_kernel, dim3(512), dim3(256), 0, stream,
                       x, wt, aw, ab, plog, feats, wmix, bstate, out);
}

// Round 6
// 123.729 us; speedup vs baseline: 1.8497x; 1.8497x over previous
//
#include <hip/hip_runtime.h>
#include <hip/hip_bf16.h>
#include <math.h>

// Shapes: x(8,64,128,128) f32; wt(4,4,64,64,3,3) f32; attn_w(4,64); attn_b(4)
// Subband space: 64x64, 4 subbands, 64 cin, 64 cout.
// feats layout: [b][sub][66][66][64c] bf16, zero border ring (pad=1).
// 3 kernels (fused single-kernel + sw grid barrier was 110us SLOWER: 512
// same-line device-scope atomics serialize ~100-200ns each at the coherence
// point -- round 5 lesson).

typedef __bf16 bf16x8 __attribute__((ext_vector_type(8)));
typedef float f32x4 __attribute__((ext_vector_type(4)));

__device__ __forceinline__ bf16x8 as_bf16x8(uint4 u) {
    union { uint4 a; bf16x8 b; } c; c.a = u; return c.b;
}
__device__ __forceinline__ unsigned short bf16bits(float f) {
    __hip_bfloat16 h = __float2bfloat16(f);
    union { __hip_bfloat16 h; unsigned short u; } c; c.h = h; return c.u;
}
// async 16B global -> LDS (DMA; LDS dest = wave-uniform base + lane*16)
__device__ __forceinline__ void gload_lds16(const uint4* g, uint4* l) {
    __builtin_amdgcn_global_load_lds(
        (const __attribute__((address_space(1))) unsigned int*)g,
        (__attribute__((address_space(3))) unsigned int*)l, 16, 0, 0);
}

#define FPLANE 34848   // 66*66*8 uint4 per (b,sub) plane
#define FROW   528     // 66*8

// ---------------------------------------------------------------------------
// K1: Haar DWT -> bf16 feats (padded, zero ring) + per-y partial logits
// grid (64 y, 8 b), 256 threads.  (verified round 2)
// ---------------------------------------------------------------------------
__global__ __launch_bounds__(256)
void dwt_kernel(const float* __restrict__ x, const float* __restrict__ attn_w,
                unsigned short* __restrict__ feats, float* __restrict__ plog) {
    __shared__ uint4 sT[2304];                     // 4 sub * 64 x * 9 chunks (72 bf16)
    __shared__ float sred[64][4];                  // [c][sub]
    unsigned short* sTu = (unsigned short*)sT;
    int y = blockIdx.x, b = blockIdx.y;
    int t = threadIdx.x;
    int c = t >> 2, q = t & 3;

    const float4* r0 = (const float4*)x + ((size_t)(b * 64 + c) * 128 + 2 * y) * 32;
    const float4* r1 = r0 + 32;

    float s0 = 0.f, s1 = 0.f, s2 = 0.f, s3 = 0.f;
    #pragma unroll
    for (int i = 0; i < 8; ++i) {
        int f = i * 4 + q;                         // quad covers 64B contiguous
        float4 p = r0[f], qq = r1[f];
        int xo = 2 * f;
        {
            float a = p.x, bb = p.y, cc = qq.x, dd = qq.y;
            float ll = (a + bb + cc + dd) * 0.5f, h0 = (a + bb - cc - dd) * 0.5f;
            float h1 = (a - bb + cc - dd) * 0.5f, hh = (a - bb - cc + dd) * 0.5f;
            s0 += ll; s1 += h0; s2 += h1; s3 += hh;
            sTu[0 * 4608 + xo * 72 + c] = bf16bits(ll);
            sTu[1 * 4608 + xo * 72 + c] = bf16bits(h0);
            sTu[2 * 4608 + xo * 72 + c] = bf16bits(h1);
            sTu[3 * 4608 + xo * 72 + c] = bf16bits(hh);
        }
        {
            float a = p.z, bb = p.w, cc = qq.z, dd = qq.w;
            float ll = (a + bb + cc + dd) * 0.5f, h0 = (a + bb - cc - dd) * 0.5f;
            float h1 = (a - bb + cc - dd) * 0.5f, hh = (a - bb - cc + dd) * 0.5f;
            s0 += ll; s1 += h0; s2 += h1; s3 += hh;
            sTu[0 * 4608 + (xo + 1) * 72 + c] = bf16bits(ll);
            sTu[1 * 4608 + (xo + 1) * 72 + c] = bf16bits(h0);
            sTu[2 * 4608 + (xo + 1) * 72 + c] = bf16bits(h1);
            sTu[3 * 4608 + (xo + 1) * 72 + c] = bf16bits(hh);
        }
    }
    s0 += __shfl_xor(s0, 1); s0 += __shfl_xor(s0, 2);
    s1 += __shfl_xor(s1, 1); s1 += __shfl_xor(s1, 2);
    s2 += __shfl_xor(s2, 1); s2 += __shfl_xor(s2, 2);
    s3 += __shfl_xor(s3, 1); s3 += __shfl_xor(s3, 2);
    if (q == 0) { sred[c][0] = s0; sred[c][1] = s1; sred[c][2] = s2; sred[c][3] = s3; }
    __syncthreads();
    if (t < 16) {
        int sub = t >> 2, k = t & 3;
        float acc = 0.f;
        #pragma unroll 8
        for (int cc = 0; cc < 64; ++cc)
            acc += attn_w[k * 64 + cc] * sred[cc][sub];
        plog[((size_t)(b * 4 + sub) * 4 + k) * 64 + y] = acc;
    }
    // padded channel-last writes: row y+1 of each plane, zero side borders
    uint4* fpad = (uint4*)feats;
    const uint4 zz = make_uint4(0u, 0u, 0u, 0u);
    for (int e = t; e < 2112; e += 256) {
        int s = e / 528, r = e - s * 528;
        int px = r >> 3, ck = r & 7;
        uint4 v = zz;
        if (px >= 1 && px <= 64) v = sT[s * 576 + (px - 1) * 9 + ck];
        fpad[((size_t)(b * 4 + s) * 66 + (y + 1)) * FROW + r] = v;
    }
    if (y == 0) {
        for (int e = t; e < 2112; e += 256) {
            int s = e / 528, r = e - s * 528;
            fpad[(size_t)(b * 4 + s) * 66 * FROW + r] = zz;
        }
    } else if (y == 63) {
        for (int e = t; e < 2112; e += 256) {
            int s = e / 528, r = e - s * 528;
            fpad[((size_t)(b * 4 + s) * 66 + 65) * FROW + r] = zz;
        }
    }
}

// ---------------------------------------------------------------------------
// K2: attention (from plog) + kernel mixing -> bf16 wmix[b][sub][tap][co][ci]
// grid (64 co, 4 sub), 256 threads.  (verified round 2)
// ---------------------------------------------------------------------------
__global__ __launch_bounds__(256)
void mix_kernel(const float* __restrict__ wt, const float* __restrict__ attn_b,
                const float* __restrict__ plog, unsigned short* __restrict__ wmix) {
    __shared__ float sLw[4][576];       // [k][ci*9+tap]
    __shared__ float satt[8][4];        // [b][k]
    int co = blockIdx.x, sub = blockIdx.y;
    int t = threadIdx.x;

    if (t < 32) {
        int b = t >> 2, k = t & 3;
        const float* pp = plog + ((size_t)(b * 4 + sub) * 4 + k) * 64;
        float acc = 0.f;
        #pragma unroll 8
        for (int yy = 0; yy < 64; ++yy) acc += pp[yy];
        float logit = acc * (1.0f / 4096.0f) + attn_b[k];
        float m = fmaxf(logit, __shfl_xor(logit, 1));
        m = fmaxf(m, __shfl_xor(m, 2));
        float e = expf(logit - m);
        float s = e + __shfl_xor(e, 1);
        s += __shfl_xor(s, 2);
        satt[b][k] = e / s;
    }
    for (int e = t; e < 2304; e += 256) {
        int k = e / 576, r = e - k * 576;
        sLw[k][r] = wt[((size_t)(k * 4 + sub) * 64 + co) * 576 + r];
    }
    __syncthreads();
    #pragma unroll
    for (int j = 0; j < 18; ++j) {
        int idx = j * 256 + t;
        int b = idx / 576;
        int r = idx - b * 576;
        int tap = r >> 6, ci = r & 63;
        int wi = ci * 9 + tap;
        float v = satt[b][0] * sLw[0][wi] + satt[b][1] * sLw[1][wi]
                + satt[b][2] * sLw[2][wi] + satt[b][3] * sLw[3][wi];
        wmix[((size_t)(b * 4 + sub) * 9 + tap) * 4096 + co * 64 + ci] = bf16bits(v);
    }
}

// ---------------------------------------------------------------------------
// K3: fused conv + Haar IDWT, 8x16 px tile x 16 couts x all 4 subbands.
// Occupancy-first revision: co-group 16 (cgv 4-way) halves the W buffer ->
// LDS 43.0 KB -> 3 blocks/CU (12 waves/CU, was 2 blocks/8 waves). Each of
// 4 waves owns 2 y-rows x 16 co; af rows fully pre-loaded (no slide).
// grid 1024 blocks (1-D; b = lin&7 keeps each XCD on one batch -> feats
// L2-resident), 256 threads. 2-phase prefetch, one __syncthreads per phase.
// 8 phases: (sub 0..3) x (ci-chunk 0..1). IDWT signs folded into accQ.
// ---------------------------------------------------------------------------
__device__ __forceinline__ void stage_A(const uint4* __restrict__ fp, uint4* sAb,
                                        int y0, int x0, int ck8, int t) {
    // A halo: 10x18 px * 4 g-chunks (32 ci) = 720 uint4; padded to 768
    // (e 720..767 read row y0+10 -- garbage within allocated ws, never consumed)
    #pragma unroll
    for (int i = 0; i < 3; ++i) {
        int e = t + i * 256;
        int py = e / 72, rr = e - py * 72, px = rr >> 2, g = rr & 3;
        gload_lds16(fp + (size_t)((y0 + py) * 66 + x0 + px) * 8 + ck8 + g, &sAb[e]);
    }
}
// W: 9 taps x 16 co (this cgv quarter) x 32 ci = 576 uint4
__device__ __forceinline__ void stage_W(const uint4* __restrict__ wch, uint4* sWb,
                                        int cgv, int ck8, int t) {
    #pragma unroll
    for (int i = 0; i < 2; ++i) {
        int e = t + i * 256;                       // 0..511
        int tap = e >> 6, rr = e & 63, co = rr >> 2, g = rr & 3;
        gload_lds16(wch + tap * 512 + (cgv * 16 + co) * 8 + ck8 + g, &sWb[e]);
    }
    if (t < 64) {                                  // tail 512..575: wave 0 (uniform)
        int e = 512 + t;
        int tap = e >> 6, rr = e & 63, co = rr >> 2, g = rr & 3;
        gload_lds16(wch + tap * 512 + (cgv * 16 + co) * 8 + ck8 + g, &sWb[e]);
    }
}

__global__ __launch_bounds__(256, 3)
void conv_idwt_kernel(const unsigned short* __restrict__ feats,
                      const unsigned short* __restrict__ wmix,
                      float* __restrict__ out) {
    __shared__ uint4 sA[2][768];       // double-buffered A halo (10x18x4 + pad)
    __shared__ uint4 sW[2][576];       // double-buffered weights (16 co)
    int lin = blockIdx.x;
    int b = lin & 7;                   // XCD-chunked: XCD k -> batch k
    int rest = lin >> 3;               // [0,128)
    int cgv = rest >> 5, tile = rest & 31;
    int y0 = (tile >> 2) * 8, x0 = (tile & 3) * 16;
    int t = threadIdx.x, w = t >> 6, l = t & 63;
    int l16 = l & 15, kg = l >> 4;
    int wy2 = w * 2;                   // 2 y-rows per wave

    const uint4* fpb = (const uint4*)feats + (size_t)b * 4 * FPLANE;
    const uint4* wcb = (const uint4*)wmix + (size_t)b * 4 * 4608;

    f32x4 accQ[4][2];                  // [quad a,b,c,d][r]
    f32x4 accS[2];                     // current-subband conv accumulator
    #pragma unroll
    for (int qd = 0; qd < 4; ++qd)
        #pragma unroll
        for (int r = 0; r < 2; ++r)
            accQ[qd][r] = (f32x4){0.f, 0.f, 0.f, 0.f};
    #pragma unroll
    for (int r = 0; r < 2; ++r) accS[r] = (f32x4){0.f, 0.f, 0.f, 0.f};

    // prologue: stage phase 0 (sub 0, chunk 0)
    stage_A(fpb, sA[0], y0, x0, 0, t);
    stage_W(wcb, sW[0], cgv, 0, t);
    __syncthreads();

    #pragma unroll
    for (int p = 0; p < 8; ++p) {
        const int sub = p >> 1;
        // issue next phase's loads first -- they land during the MFMA stretch
        if (p < 7) {
            const int ns = (p + 1) >> 1, nc = ((p + 1) & 1) * 4;
            stage_A(fpb + (size_t)ns * FPLANE, sA[(p + 1) & 1], y0, x0, nc, t);
            stage_W(wcb + (size_t)ns * 4608, sW[(p + 1) & 1], cgv, nc, t);
        }
        // compute current phase from buffer p&1
        {
            const uint4* A = sA[p & 1];
            const uint4* W = sW[p & 1];
            uint4 af[4][3];            // input rows wy2..wy2+3 x 3 dx
            #pragma unroll
            for (int i = 0; i < 4; ++i)
                #pragma unroll
                for (int dx = 0; dx < 3; ++dx)
                    af[i][dx] = A[((wy2 + i) * 18 + l16 + dx) * 4 + kg];
            __builtin_amdgcn_s_setprio(1);
            #pragma unroll
            for (int dy = 0; dy < 3; ++dy) {
                #pragma unroll
                for (int dx = 0; dx < 3; ++dx) {
                    int tap = dy * 3 + dx;
                    bf16x8 bw = as_bf16x8(W[tap * 64 + l16 * 4 + kg]);
                    #pragma unroll
                    for (int r = 0; r < 2; ++r)
                        accS[r] = __builtin_amdgcn_mfma_f32_16x16x32_bf16(
                            as_bf16x8(af[dy + r][dx]), bw, accS[r], 0, 0, 0);
                }
            }
            __builtin_amdgcn_s_setprio(0);
        }
        // end of subband: fold into quad accumulators with IDWT signs
        // a: + + + +   b: + + - -   c: + - + -   d: + - - +   (over ll,h0,h1,hh)
        if (p & 1) {
            const float g1 = (sub <= 1) ? 1.f : -1.f;
            const float g2 = (sub == 0 || sub == 2) ? 1.f : -1.f;
            const float g3 = (sub == 0 || sub == 3) ? 1.f : -1.f;
            #pragma unroll
            for (int r = 0; r < 2; ++r) {
                #pragma unroll
                for (int j = 0; j < 4; ++j) {
                    float v = accS[r][j];
                    accQ[0][r][j] += v;
                    accQ[1][r][j] += g1 * v;
                    accQ[2][r][j] += g2 * v;
                    accQ[3][r][j] += g3 * v;
                    accS[r][j] = 0.f;
                }
            }
        }
        __syncthreads();
    }

    // epilogue: D row=(lane>>4)*4+reg = x offset, col=lane&15 = co (within 16)
    // subband pixel (y,x) -> out rows 2y (a,b interleaved), 2y+1 (c,d)
    #pragma unroll
    for (int r = 0; r < 2; ++r) {
        int y = y0 + wy2 + r;
        int co = cgv * 16 + l16;
        float* otop = out + ((size_t)(b * 64 + co) * 128 + 2 * y) * 128
                          + 2 * (x0 + kg * 4);
        float* obot = otop + 128;
        #pragma unroll
        for (int jp = 0; jp < 2; ++jp) {
            float4 vt, vb;
            vt.x = 0.5f * accQ[0][r][2 * jp];
            vt.y = 0.5f * accQ[1][r][2 * jp];
            vt.z = 0.5f * accQ[0][r][2 * jp + 1];
            vt.w = 0.5f * accQ[1][r][2 * jp + 1];
            vb.x = 0.5f * accQ[2][r][2 * jp];
            vb.y = 0.5f * accQ[3][r][2 * jp];
            vb.z = 0.5f * accQ[2][r][2 * jp + 1];
            vb.w = 0.5f * accQ[3][r][2 * jp + 1];
            *(float4*)(otop + 4 * jp) = vt;
            *(float4*)(obot + 4 * jp) = vb;
        }
    }
}

// ---------------------------------------------------------------------------
extern "C" void kernel_launch(void* const* d_in, const int* in_sizes, int n_in,
                              void* d_out, int out_size, void* d_ws, size_t ws_size,
                              hipStream_t stream) {
    const float* x  = (const float*)d_in[0];
    const float* wt = (const float*)d_in[1];
    const float* aw = (const float*)d_in[2];
    const float* ab = (const float*)d_in[3];
    float* out = (float*)d_out;
    char* ws = (char*)d_ws;

    float* plog           = (float*)ws;                              // 32,768 B
    unsigned short* feats = (unsigned short*)(ws + 32768);           // 17,842,176 B (padded)
    unsigned short* wmix  = (unsigned short*)(ws + 32768 + 17842176);// 2,359,296 B

    hipLaunchKernelGGL(dwt_kernel, dim3(64, 8), dim3(256), 0, stream, x, aw, feats, plog);
    hipLaunchKernelGGL(mix_kernel, dim3(64, 4), dim3(256), 0, stream, wt, ab, plog, wmix);
    hipLaunchKernelGGL(conv_idwt_kernel, dim3(1024), dim3(256), 0, stream,
                       feats, wmix, out);
}

// Round 7
// 117.182 us; speedup vs baseline: 1.9530x; 1.0559x over previous
//
#include <hip/hip_runtime.h>
#include <hip/hip_bf16.h>
#include <math.h>

// Shapes: x(8,64,128,128) f32; wt(4,4,64,64,3,3) f32; attn_w(4,64); attn_b(4)
// Subband space: 64x64, 4 subbands, 64 cin, 64 cout.
// feats layout (chunk-major): [b][sub][half(2)][66][66][32ci] bf16, zero ring.
//   -> each conv phase reads fully contiguous 64B-per-px runs (full L1 lines),
//      vs the old [..][66][66][64ci] layout where each phase read 64B-of-128B.
// wmix layout (chunk-major): [b][sub][chunk(2)][tap(9)][co(64)][32ci] bf16.
// 3 kernels; R2 structure (verified 117.0) otherwise unchanged.

typedef __bf16 bf16x8 __attribute__((ext_vector_type(8)));
typedef float f32x4 __attribute__((ext_vector_type(4)));

__device__ __forceinline__ bf16x8 as_bf16x8(uint4 u) {
    union { uint4 a; bf16x8 b; } c; c.a = u; return c.b;
}
__device__ __forceinline__ unsigned short bf16bits(float f) {
    __hip_bfloat16 h = __float2bfloat16(f);
    union { __hip_bfloat16 h; unsigned short u; } c; c.h = h; return c.u;
}
// async 16B global -> LDS (DMA; LDS dest = wave-uniform base + lane*16)
__device__ __forceinline__ void gload_lds16(const uint4* g, uint4* l) {
    __builtin_amdgcn_global_load_lds(
        (const __attribute__((address_space(1))) unsigned int*)g,
        (__attribute__((address_space(3))) unsigned int*)l, 16, 0, 0);
}

#define FPLANE 34848   // 2 halves * 66*66*4 uint4 per (b,sub) plane
#define FHALF  17424   // 66*66*4 uint4 per half-plane (32 ci)
#define FROW2  264     // 66*4 uint4 per row within a half-plane

// ---------------------------------------------------------------------------
// K1: Haar DWT -> bf16 feats (padded, zero ring, chunk-major) + partial logits
// grid (64 y, 8 b), 256 threads.
// ---------------------------------------------------------------------------
__global__ __launch_bounds__(256)
void dwt_kernel(const float* __restrict__ x, const float* __restrict__ attn_w,
                unsigned short* __restrict__ feats, float* __restrict__ plog) {
    __shared__ uint4 sT[2304];                     // 4 sub * 64 x * 9 chunks (72 bf16)
    __shared__ float sred[64][4];                  // [c][sub]
    unsigned short* sTu = (unsigned short*)sT;
    int y = blockIdx.x, b = blockIdx.y;
    int t = threadIdx.x;
    int c = t >> 2, q = t & 3;

    const float4* r0 = (const float4*)x + ((size_t)(b * 64 + c) * 128 + 2 * y) * 32;
    const float4* r1 = r0 + 32;

    float s0 = 0.f, s1 = 0.f, s2 = 0.f, s3 = 0.f;
    #pragma unroll
    for (int i = 0; i < 8; ++i) {
        int f = i * 4 + q;                         // quad covers 64B contiguous
        float4 p = r0[f], qq = r1[f];
        int xo = 2 * f;
        {
            float a = p.x, bb = p.y, cc = qq.x, dd = qq.y;
            float ll = (a + bb + cc + dd) * 0.5f, h0 = (a + bb - cc - dd) * 0.5f;
            float h1 = (a - bb + cc - dd) * 0.5f, hh = (a - bb - cc + dd) * 0.5f;
            s0 += ll; s1 += h0; s2 += h1; s3 += hh;
            sTu[0 * 4608 + xo * 72 + c] = bf16bits(ll);
            sTu[1 * 4608 + xo * 72 + c] = bf16bits(h0);
            sTu[2 * 4608 + xo * 72 + c] = bf16bits(h1);
            sTu[3 * 4608 + xo * 72 + c] = bf16bits(hh);
        }
        {
            float a = p.z, bb = p.w, cc = qq.z, dd = qq.w;
            float ll = (a + bb + cc + dd) * 0.5f, h0 = (a + bb - cc - dd) * 0.5f;
            float h1 = (a - bb + cc - dd) * 0.5f, hh = (a - bb - cc + dd) * 0.5f;
            s0 += ll; s1 += h0; s2 += h1; s3 += hh;
            sTu[0 * 4608 + (xo + 1) * 72 + c] = bf16bits(ll);
            sTu[1 * 4608 + (xo + 1) * 72 + c] = bf16bits(h0);
            sTu[2 * 4608 + (xo + 1) * 72 + c] = bf16bits(h1);
            sTu[3 * 4608 + (xo + 1) * 72 + c] = bf16bits(hh);
        }
    }
    s0 += __shfl_xor(s0, 1); s0 += __shfl_xor(s0, 2);
    s1 += __shfl_xor(s1, 1); s1 += __shfl_xor(s1, 2);
    s2 += __shfl_xor(s2, 1); s2 += __shfl_xor(s2, 2);
    s3 += __shfl_xor(s3, 1); s3 += __shfl_xor(s3, 2);
    if (q == 0) { sred[c][0] = s0; sred[c][1] = s1; sred[c][2] = s2; sred[c][3] = s3; }
    __syncthreads();
    if (t < 16) {
        int sub = t >> 2, k = t & 3;
        float acc = 0.f;
        #pragma unroll 8
        for (int cc = 0; cc < 64; ++cc)
            acc += attn_w[k * 64 + cc] * sred[cc][sub];
        plog[((size_t)(b * 4 + sub) * 4 + k) * 64 + y] = acc;
    }
    // chunk-major padded writes: row y+1 of each half-plane, zero side borders
    uint4* fpad = (uint4*)feats;
    const uint4 zz = make_uint4(0u, 0u, 0u, 0u);
    for (int e = t; e < 2112; e += 256) {
        int s = e / 528, r = e - s * 528;
        int px = r >> 3, ck = r & 7;               // ck: 8 uint4 = 64 ci
        uint4 v = zz;
        if (px >= 1 && px <= 64) v = sT[s * 576 + (px - 1) * 9 + ck];
        int h = ck >> 2, g = ck & 3;
        fpad[(((size_t)(b * 4 + s) * 2 + h) * 66 + (y + 1)) * FROW2 + px * 4 + g] = v;
    }
    if (y == 0) {
        for (int e = t; e < 2112; e += 256) {
            int s = e / 528, r = e - s * 528;
            int px = r >> 3, ck = r & 7;
            int h = ck >> 2, g = ck & 3;
            fpad[((size_t)(b * 4 + s) * 2 + h) * 66 * FROW2 + px * 4 + g] = zz;
        }
    } else if (y == 63) {
        for (int e = t; e < 2112; e += 256) {
            int s = e / 528, r = e - s * 528;
            int px = r >> 3, ck = r & 7;
            int h = ck >> 2, g = ck & 3;
            fpad[(((size_t)(b * 4 + s) * 2 + h) * 66 + 65) * FROW2 + px * 4 + g] = zz;
        }
    }
}

// ---------------------------------------------------------------------------
// K2: attention (from plog) + kernel mixing -> bf16 wmix (chunk-major)
// grid (64 co, 4 sub), 256 threads.
// ---------------------------------------------------------------------------
__global__ __launch_bounds__(256)
void mix_kernel(const float* __restrict__ wt, const float* __restrict__ attn_b,
                const float* __restrict__ plog, unsigned short* __restrict__ wmix) {
    __shared__ float sLw[4][576];       // [k][ci*9+tap]
    __shared__ float satt[8][4];        // [b][k]
    int co = blockIdx.x, sub = blockIdx.y;
    int t = threadIdx.x;

    if (t < 32) {
        int b = t >> 2, k = t & 3;
        const float* pp = plog + ((size_t)(b * 4 + sub) * 4 + k) * 64;
        float acc = 0.f;
        #pragma unroll 8
        for (int yy = 0; yy < 64; ++yy) acc += pp[yy];
        float logit = acc * (1.0f / 4096.0f) + attn_b[k];
        float m = fmaxf(logit, __shfl_xor(logit, 1));
        m = fmaxf(m, __shfl_xor(m, 2));
        float e = expf(logit - m);
        float s = e + __shfl_xor(e, 1);
        s += __shfl_xor(s, 2);
        satt[b][k] = e / s;
    }
    for (int e = t; e < 2304; e += 256) {
        int k = e / 576, r = e - k * 576;
        sLw[k][r] = wt[((size_t)(k * 4 + sub) * 64 + co) * 576 + r];
    }
    __syncthreads();
    #pragma unroll
    for (int j = 0; j < 18; ++j) {
        int idx = j * 256 + t;
        int b = idx / 576;
        int r = idx - b * 576;
        int tap = r >> 6, ci = r & 63;
        int wi = ci * 9 + tap;
        float v = satt[b][0] * sLw[0][wi] + satt[b][1] * sLw[1][wi]
                + satt[b][2] * sLw[2][wi] + satt[b][3] * sLw[3][wi];
        wmix[((((size_t)(b * 4 + sub) * 2 + (ci >> 5)) * 9 + tap) * 64 + co) * 32
             + (ci & 31)] = bf16bits(v);
    }
}

// ---------------------------------------------------------------------------
// K3: fused conv + Haar IDWT, 8x16 tile x 32 co x all 4 subbands (R2 config).
// grid 512 (1-D; b = lin&7 -> XCD-batch affinity), 256 threads (4 waves),
// LDS 61.4 KB -> 2 blocks/CU. 2-phase prefetch, one __syncthreads per phase.
// 8 phases: (sub 0..3) x (ci-chunk 0..1). IDWT signs folded into accQ.
// Chunk-major layouts -> every staged run is full-L1-line contiguous.
// ---------------------------------------------------------------------------
__device__ __forceinline__ void stage_A(const uint4* __restrict__ fp, uint4* sAb,
                                        int y0, int x0, int ck8, int t) {
    // A halo: 10 rows x 18 px x 4 uint4 (32 ci) = 720; slots 720..767 are pad
    // (clamped in-bounds duplicates of row 9, never consumed)
    const uint4* fph = fp + (size_t)(ck8 >> 2) * FHALF;
    #pragma unroll
    for (int i = 0; i < 3; ++i) {
        int e = t + i * 256;
        int py = e / 72, rr = e - py * 72, px = rr >> 2, g = rr & 3;
        if (py > 9) { py = 9; }
        gload_lds16(fph + (size_t)((y0 + py) * 66 + x0 + px) * 4 + g, &sAb[e]);
    }
}
// W: 9 taps x 32 co (this cg half) x 32 ci = 1152 uint4, contiguous per tap
__device__ __forceinline__ void stage_W(const uint4* __restrict__ wch, uint4* sWb,
                                        int cg, int ck8, int t) {
    const uint4* wchh = wch + (size_t)(ck8 >> 2) * 2304;   // chunk slab 9*64*4
    #pragma unroll
    for (int i = 0; i < 4; ++i) {
        int e = t + i * 256;
        int tap = e >> 7, rr = e & 127, co = rr >> 2, g = rr & 3;
        gload_lds16(wchh + tap * 256 + (cg * 32 + co) * 4 + g, &sWb[e]);
    }
    if (t < 128) {                                  // tail: waves 0,1 (wave-uniform)
        int e = 1024 + t;
        int tap = e >> 7, rr = e & 127, co = rr >> 2, g = rr & 3;
        gload_lds16(wchh + tap * 256 + (cg * 32 + co) * 4 + g, &sWb[e]);
    }
}

__global__ __launch_bounds__(256, 2)
void conv_idwt_kernel(const unsigned short* __restrict__ feats,
                      const unsigned short* __restrict__ wmix,
                      float* __restrict__ out) {
    __shared__ uint4 sA[2][768];       // double-buffered A halo (10x18x4 + pad)
    __shared__ uint4 sW[2][1152];      // double-buffered weights
    int lin = blockIdx.x;
    int b = lin & 7;                   // XCD-chunked: XCD k -> batch k
    int rest = lin >> 3;               // [0,64)
    int cg = rest >> 5, tile = rest & 31;
    int y0 = (tile >> 2) * 8, x0 = (tile & 3) * 16;
    int t = threadIdx.x, w = t >> 6, l = t & 63;
    int l16 = l & 15, kg = l >> 4;
    int wy4 = (w >> 1) * 4, wn = w & 1;

    const uint4* fpb = (const uint4*)feats + (size_t)b * 4 * FPLANE;
    const uint4* wcb = (const uint4*)wmix + (size_t)b * 4 * 4608;

    f32x4 accQ[4][4];                  // [quad a,b,c,d][r]
    f32x4 accS[4];                     // current-subband conv accumulator
    #pragma unroll
    for (int qd = 0; qd < 4; ++qd)
        #pragma unroll
        for (int r = 0; r < 4; ++r)
            accQ[qd][r] = (f32x4){0.f, 0.f, 0.f, 0.f};
    #pragma unroll
    for (int r = 0; r < 4; ++r) accS[r] = (f32x4){0.f, 0.f, 0.f, 0.f};

    // prologue: stage phase 0 (sub 0, chunk 0)
    stage_A(fpb, sA[0], y0, x0, 0, t);
    stage_W(wcb, sW[0], cg, 0, t);
    __syncthreads();

    #pragma unroll
    for (int p = 0; p < 8; ++p) {
        const int sub = p >> 1;
        // issue next phase's loads first -- they land during the MFMA stretch
        if (p < 7) {
            const int ns = (p + 1) >> 1, nc = ((p + 1) & 1) * 4;
            stage_A(fpb + (size_t)ns * FPLANE, sA[(p + 1) & 1], y0, x0, nc, t);
            stage_W(wcb + (size_t)ns * 4608, sW[(p + 1) & 1], cg, nc, t);
        }
        // compute current phase from buffer p&1
        {
            const uint4* A = sA[p & 1];
            const uint4* W = sW[p & 1];
            uint4 af[4][3];
            #pragma unroll
            for (int i = 0; i < 4; ++i)
                #pragma unroll
                for (int dx = 0; dx < 3; ++dx)
                    af[i][dx] = A[((wy4 + i) * 18 + l16 + dx) * 4 + kg];
            __builtin_amdgcn_s_setprio(1);
            #pragma unroll
            for (int dy = 0; dy < 3; ++dy) {
                if (dy > 0) {
                    #pragma unroll
                    for (int i = 0; i < 3; ++i)
                        #pragma unroll
                        for (int dx = 0; dx < 3; ++dx)
                            af[i][dx] = af[i + 1][dx];
                    #pragma unroll
                    for (int dx = 0; dx < 3; ++dx)
                        af[3][dx] = A[((wy4 + dy + 3) * 18 + l16 + dx) * 4 + kg];
                }
                #pragma unroll
                for (int dx = 0; dx < 3; ++dx) {
                    int tap = dy * 3 + dx;
                    bf16x8 bw = as_bf16x8(W[tap * 128 + (wn * 16 + l16) * 4 + kg]);
                    #pragma unroll
                    for (int r = 0; r < 4; ++r)
                        accS[r] = __builtin_amdgcn_mfma_f32_16x16x32_bf16(
                            as_bf16x8(af[r][dx]), bw, accS[r], 0, 0, 0);
                }
            }
            __builtin_amdgcn_s_setprio(0);
        }
        // end of subband: fold into quad accumulators with IDWT signs
        // a: + + + +   b: + + - -   c: + - + -   d: + - - +   (over ll,h0,h1,hh)
        if (p & 1) {
            const float g1 = (sub <= 1) ? 1.f : -1.f;
            const float g2 = (sub == 0 || sub == 2) ? 1.f : -1.f;
            const float g3 = (sub == 0 || sub == 3) ? 1.f : -1.f;
            #pragma unroll
            for (int r = 0; r < 4; ++r) {
                #pragma unroll
                for (int j = 0; j < 4; ++j) {
                    float v = accS[r][j];
                    accQ[0][r][j] += v;
                    accQ[1][r][j] += g1 * v;
                    accQ[2][r][j] += g2 * v;
                    accQ[3][r][j] += g3 * v;
                    accS[r][j] = 0.f;
                }
            }
        }
        __syncthreads();
    }

    // epilogue: D row=(lane>>4)*4+reg = x offset, col=lane&15 = co (within 16)
    // subband pixel (y,x) -> out rows 2y (a,b interleaved), 2y+1 (c,d)
    #pragma unroll
    for (int r = 0; r < 4; ++r) {
        int y = y0 + wy4 + r;
        int co = cg * 32 + wn * 16 + l16;
        float* otop = out + ((size_t)(b * 64 + co) * 128 + 2 * y) * 128
                          + 2 * (x0 + kg * 4);
        float* obot = otop + 128;
        #pragma unroll
        for (int jp = 0; jp < 2; ++jp) {
            float4 vt, vb;
            vt.x = 0.5f * accQ[0][r][2 * jp];
            vt.y = 0.5f * accQ[1][r][2 * jp];
            vt.z = 0.5f * accQ[0][r][2 * jp + 1];
            vt.w = 0.5f * accQ[1][r][2 * jp + 1];
            vb.x = 0.5f * accQ[2][r][2 * jp];
            vb.y = 0.5f * accQ[3][r][2 * jp];
            vb.z = 0.5f * accQ[2][r][2 * jp + 1];
            vb.w = 0.5f * accQ[3][r][2 * jp + 1];
            *(float4*)(otop + 4 * jp) = vt;
            *(float4*)(obot + 4 * jp) = vb;
        }
    }
}

// ---------------------------------------------------------------------------
extern "C" void kernel_launch(void* const* d_in, const int* in_sizes, int n_in,
                              void* d_out, int out_size, void* d_ws, size_t ws_size,
                              hipStream_t stream) {
    const float* x  = (const float*)d_in[0];
    const float* wt = (const float*)d_in[1];
    const float* aw = (const float*)d_in[2];
    const float* ab = (const float*)d_in[3];
    float* out = (float*)d_out;
    char* ws = (char*)d_ws;

    float* plog           = (float*)ws;                              // 32,768 B
    unsigned short* feats = (unsigned short*)(ws + 32768);           // 17,842,176 B (padded)
    unsigned short* wmix  = (unsigned short*)(ws + 32768 + 17842176);// 2,359,296 B

    hipLaunchKernelGGL(dwt_kernel, dim3(64, 8), dim3(256), 0, stream, x, aw, feats, plog);
    hipLaunchKernelGGL(mix_kernel, dim3(64, 4), dim3(256), 0, stream, wt, ab, plog, wmix);
    hipLaunchKernelGGL(conv_idwt_kernel, dim3(512), dim3(256), 0, stream,
                       feats, wmix, out);
}